// Round 1
// 474.064 us; speedup vs baseline: 1.0393x; 1.0393x over previous
//
#include <hip/hip_runtime.h>
#include <hip/hip_bf16.h>

#define NN 64
#define CI 128
#define HD 128
#define KC 5
#define SXS 136   // sx row stride in halfwords: 272 B -> 2-way-max conflicts on MFMA frag reads
#define AJW 17    // byte-packed adj row stride in words (16 used + 1 pad)

// ws layout (floats): [0,9216) Wpk B-fragments (36 frags x 64 lanes x 8 bf16)
//                     [9216,9344) z = W2 @ Wl ; ws[9344] = b1.z ; ws[9345] = b2.Wl
#define WS_Z   9216
#define WS_B1Z 9344
#define WS_B2W 9345

typedef float v4f __attribute__((ext_vector_type(4)));
typedef __bf16 v8bf __attribute__((ext_vector_type(8)));
typedef unsigned short us8 __attribute__((ext_vector_type(8)));

__device__ __forceinline__ float us2f(unsigned short u) {
    union { unsigned i; float f; } v; v.i = ((unsigned)u) << 16; return v.f;
}
__device__ __forceinline__ unsigned short f2us(float f) {
    __hip_bfloat16 h = __float2bfloat16(f);
    return *reinterpret_cast<unsigned short*>(&h);
}

// ---------------- pre-kernel: weights-only folding + B-fragment packing ----------------
extern "C" __global__ void zprep(const float* __restrict__ W1,
                                 const float* __restrict__ Wp,
                                 const float* __restrict__ W2,
                                 const float* __restrict__ Wl,
                                 const float* __restrict__ b1,
                                 const float* __restrict__ b2,
                                 float* __restrict__ ws)
{
    const int b = blockIdx.x, t = threadIdx.x;   // 64 threads
    if (b < 36) {
        const int ct = b >> 2, ks = b & 3;
        const int q = t >> 4, m16 = t & 15;
        const int k0 = ks * 32 + q * 8;
        us8 pk;
        #pragma unroll
        for (int j = 0; j < 8; ++j) {
            const int k = k0 + j;
            float v;
            if (ct < 8)      v = W1[k * HD + ct * 16 + m16];
            else             v = (m16 < KC) ? Wp[k * KC + m16] : 0.f;
            pk[j] = f2us(v);
        }
        reinterpret_cast<us8*>(ws)[b * 64 + t] = pk;
    } else if (b == 36) {
        float a0 = 0.f, a1 = 0.f;
        for (int c = 0; c < HD; ++c) {
            const float wl = Wl[c];
            a0 += W2[t * HD + c] * wl;
            a1 += W2[(t + 64) * HD + c] * wl;
        }
        ws[WS_Z + t] = a0;
        ws[WS_Z + 64 + t] = a1;
        float p1 = b1[t] * a0 + b1[t + 64] * a1;
        float p2 = b2[t] * Wl[t] + b2[t + 64] * Wl[t + 64];
        #pragma unroll
        for (int off = 32; off; off >>= 1) {
            p1 += __shfl_down(p1, off, 64);
            p2 += __shfl_down(p2, off, 64);
        }
        if (t == 0) { ws[WS_B1Z] = p1; ws[WS_B2W] = p2; }
    }
}

// ---------------- main kernel: one block per graph, 5 blocks/CU ----------------
extern "C" __global__ __launch_bounds__(256, 5)
void diffpool_main(const float* __restrict__ x,
                   const int* __restrict__ ei,
                   const float* __restrict__ bp,
                   const float* __restrict__ bl,
                   const float* __restrict__ ws,
                   float* __restrict__ out,
                   int E, int epg)
{
    __shared__ __attribute__((aligned(16))) unsigned short sx[NN][SXS]; // x -> H1 (bf16 bits)
    __shared__ unsigned int sadjb[NN][AJW];  // byte-packed counts: 4 dst per word
    __shared__ float sSm[NN][KC];            // S0 (from MFMA) then softmaxed s (in place)
    __shared__ float spart[4][NN * KC];      // per-wave partials: s_pre, U, then adj^T w ([4][64])
    __shared__ float sz [HD];                // z = W2@Wl
    __shared__ float sqp[2][NN];             // q partials (2 column halves)
    __shared__ float sd [NN];                // d = rsqrt(deg_l)
    __shared__ float sw_[NN];                // w[n] = d[n] * (s[n].coef)
    __shared__ unsigned int srdeg[NN];       // raw row degree (edge count per src)
    __shared__ float spp[4][25];             // adjp partials
    __shared__ float sadjp[25];
    __shared__ float sd2[KC];
    __shared__ float scoef[KC + 1];          // [KC] = cb = sum_n s[n].coef

    const int t = threadIdx.x;
    const int g = blockIdx.x;
    const int lane = t & 63;
    const int wv = t >> 6;
    const int n = lane;      // node owned in the split stages
    const int h = wv;        // m-quarter owned in the split stages

    // ---- prefetch this thread's edges (latency hides under P1) ----
    int e0s = -1, e0d = 0, e1s = -1, e1d = 0;
    const int base = g * epg;
    if (t < epg)       { e0s = ei[base + t] & 63;        e0d = ei[E + base + t] & 63; }
    if (t + 256 < epg) { e1s = ei[base + t + 256] & 63;  e1d = ei[E + base + t + 256] & 63; }

    // ---- P1: zero adj+deg; stage x (f32->bf16); load z ----
    {
        unsigned int* ap = &sadjb[0][0];
        for (int i = t; i < NN * AJW; i += 256) ap[i] = 0u;
        if (t < NN) srdeg[t] = 0u;
        const float* xg = x + (size_t)g * (NN * CI);
        #pragma unroll
        for (int i = 0; i < 4; ++i) {
            const int idx = t + 256 * i;          // 1024 chunks = 64 rows x 16
            const int row = idx >> 4, ch = idx & 15;
            const float4 v0 = *reinterpret_cast<const float4*>(xg + row * CI + ch * 8);
            const float4 v1 = *reinterpret_cast<const float4*>(xg + row * CI + ch * 8 + 4);
            us8 pk;
            pk[0] = f2us(v0.x); pk[1] = f2us(v0.y); pk[2] = f2us(v0.z); pk[3] = f2us(v0.w);
            pk[4] = f2us(v1.x); pk[5] = f2us(v1.y); pk[6] = f2us(v1.z); pk[7] = f2us(v1.w);
            *reinterpret_cast<us8*>(&sx[row][ch * 8]) = pk;
        }
        if (t < 32)
            reinterpret_cast<float4*>(sz)[t] = reinterpret_cast<const float4*>(ws + WS_Z)[t];
    }
    __syncthreads();

    // ---- P2: adjacency counts (byte-packed) + row degrees via LDS atomics ----
    {
        if (e0s >= 0) {
            atomicAdd(&sadjb[e0s][e0d >> 2], 1u << ((e0d & 3) * 8));
            atomicAdd(&srdeg[e0s], 1u);
        }
        if (e1s >= 0) {
            atomicAdd(&sadjb[e1s][e1d >> 2], 1u << ((e1d & 3) * 8));
            atomicAdd(&srdeg[e1s], 1u);
        }
        for (int j = t + 512; j < epg; j += 256) {   // generic tail (epg > 512)
            const int sn = ei[base + j] & 63;
            const int dn = ei[E + base + j] & 63;
            atomicAdd(&sadjb[sn][dn >> 2], 1u << ((dn & 3) * 8));
            atomicAdd(&srdeg[sn], 1u);
        }
    }
    __syncthreads();

    // ---- P3: MFMA [H1|S0] = x @ [W1|Wp'] ; degrees d (no loop) ----
    {
        const int m16 = lane & 15;
        const int q = lane >> 4;
        const int arow = wv * 16 + m16;
        v8bf afrag[4];
        #pragma unroll
        for (int ks = 0; ks < 4; ++ks)
            afrag[ks] = *reinterpret_cast<const v8bf*>(&sx[arow][ks * 32 + q * 8]);
        const v8bf* wpk = reinterpret_cast<const v8bf*>(ws);
        #pragma unroll
        for (int ct = 0; ct < 9; ++ct) {
            v4f acc = {0.f, 0.f, 0.f, 0.f};
            #pragma unroll
            for (int ks = 0; ks < 4; ++ks) {
                const v8bf bfrag = wpk[(ct * 4 + ks) * 64 + lane];
                acc = __builtin_amdgcn_mfma_f32_16x16x32_bf16(afrag[ks], bfrag, acc, 0, 0, 0);
            }
            // C/D: col = lane&15, row = q*4 + r
            if (ct < 8) {
                #pragma unroll
                for (int r = 0; r < 4; ++r)
                    sx[wv * 16 + q * 4 + r][ct * 16 + m16] = f2us(acc[r]);
            } else if (m16 < KC) {
                #pragma unroll
                for (int r = 0; r < 4; ++r)
                    sSm[wv * 16 + q * 4 + r][m16] = acc[r];
            }
        }
    }
    if (t < NN) {
        const unsigned self = (sadjb[t][t >> 2] >> ((t & 3) * 8)) & 255u;
        sd[t] = rsqrtf((float)(srdeg[t] + 1u - self));   // deg >= 1 always
    }
    __syncthreads();

    // ---- S1: s_pre partials — wave h covers m in [16h,16h+16) ----
    {
        float a0 = 0.f, a1 = 0.f, a2 = 0.f, a3 = 0.f, a4 = 0.f;
        #pragma unroll
        for (int i = 0; i < 4; ++i) {
            const unsigned w = sadjb[n][h * 4 + i];
            #pragma unroll
            for (int b = 0; b < 4; ++b) {
                const int m = h * 16 + i * 4 + b;
                const float al = (m == n) ? 1.f : (float)((w >> (b * 8)) & 255u);
                const float f = al * sd[m];
                a0 += f * sSm[m][0]; a1 += f * sSm[m][1]; a2 += f * sSm[m][2];
                a3 += f * sSm[m][3]; a4 += f * sSm[m][4];
            }
        }
        float* pp = &spart[h][n * KC];
        pp[0] = a0; pp[1] = a1; pp[2] = a2; pp[3] = a3; pp[4] = a4;
    }
    __syncthreads();

    // ---- S2: wave0 reduce+softmax (into sSm, in place); waves 1-2 q partials ----
    if (wv == 0) {
        float a0 = spart[0][n*KC+0] + spart[1][n*KC+0] + spart[2][n*KC+0] + spart[3][n*KC+0];
        float a1 = spart[0][n*KC+1] + spart[1][n*KC+1] + spart[2][n*KC+1] + spart[3][n*KC+1];
        float a2 = spart[0][n*KC+2] + spart[1][n*KC+2] + spart[2][n*KC+2] + spart[3][n*KC+2];
        float a3 = spart[0][n*KC+3] + spart[1][n*KC+3] + spart[2][n*KC+3] + spart[3][n*KC+3];
        float a4 = spart[0][n*KC+4] + spart[1][n*KC+4] + spart[2][n*KC+4] + spart[3][n*KC+4];
        const float dn = sd[n];
        a0 = a0 * dn + bp[0]; a1 = a1 * dn + bp[1]; a2 = a2 * dn + bp[2];
        a3 = a3 * dn + bp[3]; a4 = a4 * dn + bp[4];
        const float mx = fmaxf(fmaxf(fmaxf(a0, a1), fmaxf(a2, a3)), a4);
        a0 = expf(a0 - mx); a1 = expf(a1 - mx); a2 = expf(a2 - mx);
        a3 = expf(a3 - mx); a4 = expf(a4 - mx);
        const float inv = 1.f / (a0 + a1 + a2 + a3 + a4);
        sSm[n][0] = a0 * inv; sSm[n][1] = a1 * inv; sSm[n][2] = a2 * inv;
        sSm[n][3] = a3 * inv; sSm[n][4] = a4 * inv;
    } else if (wv <= 2) {
        // q[m] = H1[m] . z over half the columns; rotate c start to break 8-way aliasing
        const int p = wv - 1, m = lane;
        float a = 0.f;
        #pragma unroll
        for (int cc = 0; cc < 8; ++cc) {
            const int c = (cc + (m >> 3)) & 7;
            const us8 hh = *reinterpret_cast<const us8*>(&sx[m][p * 64 + c * 8]);
            #pragma unroll
            for (int j = 0; j < 8; ++j) a += us2f(hh[j]) * sz[p * 64 + c * 8 + j];
        }
        sqp[p][m] = a;
    }
    __syncthreads();

    // ---- S3: U = adj @ s partials (raw adj, no diag mod) ----
    {
        float u0 = 0.f, u1 = 0.f, u2 = 0.f, u3 = 0.f, u4 = 0.f;
        #pragma unroll
        for (int i = 0; i < 4; ++i) {
            const unsigned w = sadjb[n][h * 4 + i];
            #pragma unroll
            for (int b = 0; b < 4; ++b) {
                const int m = h * 16 + i * 4 + b;
                const float c = (float)((w >> (b * 8)) & 255u);
                u0 += c * sSm[m][0]; u1 += c * sSm[m][1]; u2 += c * sSm[m][2];
                u3 += c * sSm[m][3]; u4 += c * sSm[m][4];
            }
        }
        float* pp = &spart[h][n * KC];
        pp[0] = u0; pp[1] = u1; pp[2] = u2; pp[3] = u3; pp[4] = u4;
    }
    __syncthreads();

    // ---- S4: adjp = s^T U partials (U re-reduced from spart on the fly) ----
    if (lane < 25) {
        const int k = lane / 5, l = lane - k * 5;
        float a = 0.f;
        #pragma unroll
        for (int i = 0; i < 16; ++i) {
            const int m = h * 16 + i;
            const float u = spart[0][m*KC+l] + spart[1][m*KC+l] +
                            spart[2][m*KC+l] + spart[3][m*KC+l];
            a += sSm[m][k] * u;
        }
        spp[h][lane] = a;
    }
    __syncthreads();

    // ---- S5: wave0 scalar chain (adjp -> d2 -> coef -> w, cb); wave-internal LDS order ----
    if (wv == 0) {
        if (lane < 25)
            sadjp[lane] = spp[0][lane] + spp[1][lane] + spp[2][lane] + spp[3][lane];
        if (lane < KC) {
            float s_ = 0.f;
            #pragma unroll
            for (int l = 0; l < KC; ++l) s_ += sadjp[lane * KC + l];
            s_ += 1.f - sadjp[lane * 6];
            sd2[lane] = rsqrtf(fmaxf(s_, 1.f));
        }
        if (lane < KC) {
            float a = 0.f;
            #pragma unroll
            for (int k = 0; k < KC; ++k) a += sd2[k] * sadjp[k * KC + lane];
            a += sd2[lane] * (1.f - sadjp[lane * 6]);
            scoef[lane] = sd2[lane] * a;
        }
        float t5 = scoef[0] * sSm[n][0] + scoef[1] * sSm[n][1] + scoef[2] * sSm[n][2] +
                   scoef[3] * sSm[n][3] + scoef[4] * sSm[n][4];
        sw_[n] = sd[n] * t5;
        #pragma unroll
        for (int off = 32; off; off >>= 1) t5 += __shfl_down(t5, off, 64);
        if (lane == 0) scoef[KC] = t5;           // cb
    }
    __syncthreads();

    // ---- S6: a[m] = sum_n w[n]*adj_l[n][m] partials — wave h covers n in [16h,16h+16) ----
    {
        float pa = 0.f;
        #pragma unroll
        for (int i = 0; i < 16; ++i) {
            const int nn2 = h * 16 + i;
            const float al = (nn2 == n) ? 1.f
                           : (float)((sadjb[nn2][n >> 2] >> ((n & 3) * 8)) & 255u);
            pa += sw_[nn2] * al;
        }
        spart[h][n] = pa;
    }
    __syncthreads();

    // ---- S7: wave0 final: out = sum_m d[m]*a[m]*q[m] + cb*b1z + 5*b2wl + bl ----
    if (wv == 0) {
        const float a = spart[0][n] + spart[1][n] + spart[2][n] + spart[3][n];
        const float qm = sqp[0][n] + sqp[1][n];
        float v = sd[n] * a * qm;
        #pragma unroll
        for (int off = 32; off; off >>= 1) v += __shfl_down(v, off, 64);
        if (lane == 0)
            out[g] = v + scoef[KC] * ws[WS_B1Z] + 5.f * ws[WS_B2W] + bl[0];
    }
}

extern "C" void kernel_launch(void* const* d_in, const int* in_sizes, int n_in,
                              void* d_out, int out_size, void* d_ws, size_t ws_size,
                              hipStream_t stream) {
    const float* x  = (const float*)d_in[0];
    const int*   ei = (const int*)d_in[1];
    // d_in[2] = batch (layout implied; unused)
    const float* Wp = (const float*)d_in[3];
    const float* bp = (const float*)d_in[4];
    const float* W1 = (const float*)d_in[5];
    const float* b1 = (const float*)d_in[6];
    const float* W2 = (const float*)d_in[7];
    const float* b2 = (const float*)d_in[8];
    const float* Wl = (const float*)d_in[9];
    const float* bl = (const float*)d_in[10];
    float* out = (float*)d_out;
    float* ws  = (float*)d_ws;

    const int B = out_size;            // 8192 graphs
    const int E = in_sizes[1] / 2;     // edge_index is [2, E]
    const int epg = E / B;             // 512 edges per graph

    zprep<<<37, 64, 0, stream>>>(W1, Wp, W2, Wl, b1, b2, ws);
    diffpool_main<<<B, 256, 0, stream>>>(x, ei, bp, bl, ws, out, E, epg);
}

// Round 2
// 423.580 us; speedup vs baseline: 1.1631x; 1.1192x over previous
//
#include <hip/hip_runtime.h>
#include <hip/hip_bf16.h>

#define NN 64
#define CI 128
#define HD 128
#define KC 5
#define SXS 136   // sx row stride in halfwords: 272 B, 16B-aligned rows
#define AJW 17    // byte-packed adj row stride in words (16 used + 1 pad)

// ws layout (floats): [0,1024) Wp B-fragments (4 frags x 64 lanes x 8 bf16)
//                     [1024,1152) y = W1 @ W2 @ Wl ; ws[1152] = b1.z ; ws[1153] = b2.Wl
#define WS_Y   1024
#define WS_B1Z 1152
#define WS_B2W 1153

typedef float v4f __attribute__((ext_vector_type(4)));
typedef __bf16 v8bf __attribute__((ext_vector_type(8)));
typedef unsigned short us8 __attribute__((ext_vector_type(8)));

__device__ __forceinline__ unsigned short f2us(float f) {
    __hip_bfloat16 h = __float2bfloat16(f);
    return *reinterpret_cast<unsigned short*>(&h);
}

// ---------------- pre-kernel: weights-only folding + B-fragment packing ----------------
extern "C" __global__ void zprep(const float* __restrict__ W1,
                                 const float* __restrict__ Wp,
                                 const float* __restrict__ W2,
                                 const float* __restrict__ Wl,
                                 const float* __restrict__ b1,
                                 const float* __restrict__ b2,
                                 float* __restrict__ ws)
{
    const int b = blockIdx.x, t = threadIdx.x;   // 64 threads
    if (b < 4) {
        // B-frag for ct=8 (Wp columns), k-slice ks=b: n=lane&15, k=ks*32+(lane>>4)*8+j
        const int ks = b;
        const int q = t >> 4, m16 = t & 15;
        const int k0 = ks * 32 + q * 8;
        us8 pk;
        #pragma unroll
        for (int j = 0; j < 8; ++j) {
            const int k = k0 + j;
            pk[j] = f2us((m16 < KC) ? Wp[k * KC + m16] : 0.f);
        }
        reinterpret_cast<us8*>(ws)[b * 64 + t] = pk;
    } else {   // b == 4: z = W2@Wl, then y = W1@z, b1z, b2wl
        __shared__ float sz_[HD];
        float a0 = 0.f, a1 = 0.f;
        for (int c = 0; c < HD; ++c) {
            const float wl = Wl[c];
            a0 += W2[t * HD + c] * wl;
            a1 += W2[(t + 64) * HD + c] * wl;
        }
        sz_[t] = a0; sz_[t + 64] = a1;
        float p1 = b1[t] * a0 + b1[t + 64] * a1;
        float p2 = b2[t] * Wl[t] + b2[t + 64] * Wl[t + 64];
        #pragma unroll
        for (int off = 32; off; off >>= 1) {
            p1 += __shfl_down(p1, off, 64);
            p2 += __shfl_down(p2, off, 64);
        }
        if (t == 0) { ws[WS_B1Z] = p1; ws[WS_B2W] = p2; }
        __syncthreads();
        #pragma unroll
        for (int rr = 0; rr < 2; ++rr) {
            const int r = t + rr * 64;
            float acc = 0.f;
            for (int h2 = 0; h2 < HD; ++h2) acc += W1[r * HD + h2] * sz_[h2];
            ws[WS_Y + r] = acc;
        }
    }
}

// ---------------- main kernel: one block per graph, 6 blocks/CU ----------------
extern "C" __global__ __launch_bounds__(256, 6)
void diffpool_main(const float* __restrict__ x,
                   const int* __restrict__ ei,
                   const float* __restrict__ bp,
                   const float* __restrict__ bl,
                   const float* __restrict__ ws,
                   float* __restrict__ out,
                   int E, int epg)
{
    // sx is dead after the S0 MFMA -> alias the partial buffers into it
    __shared__ __attribute__((aligned(16))) union {
        unsigned short sx[NN][SXS];                 // 17408 B (x as bf16 for MFMA)
        struct {
            float A[4][NN * KC];                    // s_pre partials, later adj^T w partials
            float Bu[4][NN * KC];                   // U partials
            float pp[4][25];                        // adjp partials
        } s;
    } u;
    __shared__ unsigned int sadjb[NN][AJW];  // byte-packed counts: 4 dst per word
    __shared__ float sSm[NN][KC];            // S0 (MFMA out) then softmaxed s (in place)
    __shared__ float sq[NN];                 // q[m] = x[m].y  (fused into P1)
    __shared__ float sd[NN];                 // d = rsqrt(deg_l)
    __shared__ float sw_[NN];                // w[n] = d[n] * (s[n].coef)
    __shared__ unsigned int srdeg[NN];       // raw row degree
    __shared__ float sadjp[25];
    __shared__ float sd2[KC];
    __shared__ float scoef[KC];

    const int t = threadIdx.x;
    const int g = blockIdx.x;
    const int lane = t & 63;
    const int wv = t >> 6;
    const int n = lane;      // node owned in split stages
    const int h = wv;        // m-quarter owned in split stages

    // uniform scalars (SGPR loads, issued early)
    const float bp0 = bp[0], bp1 = bp[1], bp2 = bp[2], bp3 = bp[3], bp4 = bp[4];
    const float c_b1z = ws[WS_B1Z], c_b2w = ws[WS_B2W], c_bl = bl[0];

    // per-thread y chunk for fused q (L2-hot)
    const int ch = t & 15;
    const float4 y0 = *reinterpret_cast<const float4*>(ws + WS_Y + ch * 8);
    const float4 y1 = *reinterpret_cast<const float4*>(ws + WS_Y + ch * 8 + 4);

    // edge prefetch (HBM latency hides under P1)
    int e0s = -1, e0d = 0, e1s = -1, e1d = 0;
    const int base = g * epg;
    if (t < epg)       { e0s = ei[base + t] & 63;        e0d = ei[E + base + t] & 63; }
    if (t + 256 < epg) { e1s = ei[base + t + 256] & 63;  e1d = ei[E + base + t + 256] & 63; }

    // ---- P1: zero adj+deg; stage x (f32->bf16); fused q = x.y with width-16 reduce ----
    {
        unsigned int* ap = &sadjb[0][0];
        for (int i = t; i < NN * AJW; i += 256) ap[i] = 0u;
        if (t < NN) srdeg[t] = 0u;
        const float* xg = x + (size_t)g * (NN * CI);
        #pragma unroll
        for (int i = 0; i < 4; ++i) {
            const int row = (t >> 4) + 16 * i;
            const float4 v0 = *reinterpret_cast<const float4*>(xg + row * CI + ch * 8);
            const float4 v1 = *reinterpret_cast<const float4*>(xg + row * CI + ch * 8 + 4);
            us8 pk;
            pk[0] = f2us(v0.x); pk[1] = f2us(v0.y); pk[2] = f2us(v0.z); pk[3] = f2us(v0.w);
            pk[4] = f2us(v1.x); pk[5] = f2us(v1.y); pk[6] = f2us(v1.z); pk[7] = f2us(v1.w);
            *reinterpret_cast<us8*>(&u.sx[row][ch * 8]) = pk;
            float qp = v0.x * y0.x + v0.y * y0.y + v0.z * y0.z + v0.w * y0.w
                     + v1.x * y1.x + v1.y * y1.y + v1.z * y1.z + v1.w * y1.w;
            qp += __shfl_down(qp, 8, 16);
            qp += __shfl_down(qp, 4, 16);
            qp += __shfl_down(qp, 2, 16);
            qp += __shfl_down(qp, 1, 16);
            if (ch == 0) sq[row] = qp;
        }
    }
    __syncthreads();   // B1

    // ---- P2: adjacency atomics + MFMA S0 = x @ Wp (single column tile) ----
    {
        if (e0s >= 0) {
            atomicAdd(&sadjb[e0s][e0d >> 2], 1u << ((e0d & 3) * 8));
            atomicAdd(&srdeg[e0s], 1u);
        }
        if (e1s >= 0) {
            atomicAdd(&sadjb[e1s][e1d >> 2], 1u << ((e1d & 3) * 8));
            atomicAdd(&srdeg[e1s], 1u);
        }
        for (int j = t + 512; j < epg; j += 256) {   // generic tail
            const int sn = ei[base + j] & 63;
            const int dn = ei[E + base + j] & 63;
            atomicAdd(&sadjb[sn][dn >> 2], 1u << ((dn & 3) * 8));
            atomicAdd(&srdeg[sn], 1u);
        }
    }
    {
        const int m16 = lane & 15;
        const int q = lane >> 4;
        const int arow = wv * 16 + m16;
        const v8bf* wpk = reinterpret_cast<const v8bf*>(ws);
        v4f acc = {0.f, 0.f, 0.f, 0.f};
        #pragma unroll
        for (int ks = 0; ks < 4; ++ks) {
            const v8bf afrag = *reinterpret_cast<const v8bf*>(&u.sx[arow][ks * 32 + q * 8]);
            acc = __builtin_amdgcn_mfma_f32_16x16x32_bf16(afrag, wpk[ks * 64 + lane], acc, 0, 0, 0);
        }
        if (m16 < KC) {
            #pragma unroll
            for (int r = 0; r < 4; ++r)
                sSm[wv * 16 + q * 4 + r][m16] = acc[r];   // col=lane&15, row=q*4+r
        }
    }
    __syncthreads();   // B2   (sx dead from here; u.s.* live)

    // ---- S1: sd (redundant per wave, wave-internal order) + s_pre partials ----
    unsigned aw0, aw1, aw2, aw3;
    float dlane;
    {
        const unsigned selfb = (sadjb[lane][lane >> 2] >> ((lane & 3) * 8)) & 255u;
        dlane = rsqrtf((float)(srdeg[lane] + 1u - selfb));
        sd[lane] = dlane;            // 4 redundant identical writes: benign
        aw0 = sadjb[n][h * 4 + 0];
        aw1 = sadjb[n][h * 4 + 1];
        aw2 = sadjb[n][h * 4 + 2];
        aw3 = sadjb[n][h * 4 + 3];
        float a0 = 0.f, a1 = 0.f, a2 = 0.f, a3 = 0.f, a4 = 0.f;
        #pragma unroll
        for (int i = 0; i < 4; ++i) {
            const unsigned w = (i == 0) ? aw0 : (i == 1) ? aw1 : (i == 2) ? aw2 : aw3;
            #pragma unroll
            for (int bb = 0; bb < 4; ++bb) {
                const int m = h * 16 + i * 4 + bb;
                const float al = (m == n) ? 1.f : (float)((w >> (bb * 8)) & 255u);
                const float f = al * sd[m];      // same-wave write, broadcast read
                a0 += f * sSm[m][0]; a1 += f * sSm[m][1]; a2 += f * sSm[m][2];
                a3 += f * sSm[m][3]; a4 += f * sSm[m][4];
            }
        }
        float* pp = &u.s.A[h][n * KC];
        pp[0] = a0; pp[1] = a1; pp[2] = a2; pp[3] = a3; pp[4] = a4;
    }
    __syncthreads();   // B3

    // ---- S2+S3 fused: all-wave redundant softmax (into sSm) then U partials ----
    float s0v, s1v, s2v, s3v, s4v;
    {
        float a0 = u.s.A[0][n*KC+0] + u.s.A[1][n*KC+0] + u.s.A[2][n*KC+0] + u.s.A[3][n*KC+0];
        float a1 = u.s.A[0][n*KC+1] + u.s.A[1][n*KC+1] + u.s.A[2][n*KC+1] + u.s.A[3][n*KC+1];
        float a2 = u.s.A[0][n*KC+2] + u.s.A[1][n*KC+2] + u.s.A[2][n*KC+2] + u.s.A[3][n*KC+2];
        float a3 = u.s.A[0][n*KC+3] + u.s.A[1][n*KC+3] + u.s.A[2][n*KC+3] + u.s.A[3][n*KC+3];
        float a4 = u.s.A[0][n*KC+4] + u.s.A[1][n*KC+4] + u.s.A[2][n*KC+4] + u.s.A[3][n*KC+4];
        a0 = a0 * dlane + bp0; a1 = a1 * dlane + bp1; a2 = a2 * dlane + bp2;
        a3 = a3 * dlane + bp3; a4 = a4 * dlane + bp4;
        const float mx = fmaxf(fmaxf(fmaxf(a0, a1), fmaxf(a2, a3)), a4);
        a0 = expf(a0 - mx); a1 = expf(a1 - mx); a2 = expf(a2 - mx);
        a3 = expf(a3 - mx); a4 = expf(a4 - mx);
        const float inv = 1.f / (a0 + a1 + a2 + a3 + a4);
        s0v = a0 * inv; s1v = a1 * inv; s2v = a2 * inv; s3v = a3 * inv; s4v = a4 * inv;
        sSm[n][0] = s0v; sSm[n][1] = s1v; sSm[n][2] = s2v;   // redundant identical writes
        sSm[n][3] = s3v; sSm[n][4] = s4v;
        // U = adj @ s partials (raw adj); sSm[m] written by this same wave above
        float u0 = 0.f, u1 = 0.f, u2 = 0.f, u3 = 0.f, u4 = 0.f;
        #pragma unroll
        for (int i = 0; i < 4; ++i) {
            const unsigned w = (i == 0) ? aw0 : (i == 1) ? aw1 : (i == 2) ? aw2 : aw3;
            #pragma unroll
            for (int bb = 0; bb < 4; ++bb) {
                const int m = h * 16 + i * 4 + bb;
                const float c = (float)((w >> (bb * 8)) & 255u);
                u0 += c * sSm[m][0]; u1 += c * sSm[m][1]; u2 += c * sSm[m][2];
                u3 += c * sSm[m][3]; u4 += c * sSm[m][4];
            }
        }
        float* pp = &u.s.Bu[h][n * KC];
        pp[0] = u0; pp[1] = u1; pp[2] = u2; pp[3] = u3; pp[4] = u4;
    }
    __syncthreads();   // B4

    // ---- S4: adjp = s^T U partials ----
    if (lane < 25) {
        const int k = lane / 5, l = lane - k * 5;
        float a = 0.f;
        #pragma unroll
        for (int i = 0; i < 16; ++i) {
            const int m = h * 16 + i;
            const float uu = u.s.Bu[0][m*KC+l] + u.s.Bu[1][m*KC+l]
                           + u.s.Bu[2][m*KC+l] + u.s.Bu[3][m*KC+l];
            a += sSm[m][k] * uu;
        }
        u.s.pp[h][lane] = a;
    }
    __syncthreads();   // B5

    // ---- S5+S6 fused: all-wave redundant scalar chain, then adj_l^T w partials ----
    float cbv;
    {
        if (lane < 25)
            sadjp[lane] = u.s.pp[0][lane] + u.s.pp[1][lane] + u.s.pp[2][lane] + u.s.pp[3][lane];
        if (lane < KC) {
            float s_ = 0.f;
            #pragma unroll
            for (int l = 0; l < KC; ++l) s_ += sadjp[lane * KC + l];
            s_ += 1.f - sadjp[lane * 6];
            sd2[lane] = rsqrtf(fmaxf(s_, 1.f));
        }
        if (lane < KC) {
            float a = 0.f;
            #pragma unroll
            for (int k = 0; k < KC; ++k) a += sd2[k] * sadjp[k * KC + lane];
            a += sd2[lane] * (1.f - sadjp[lane * 6]);
            scoef[lane] = sd2[lane] * a;
        }
        float t5 = scoef[0] * s0v + scoef[1] * s1v + scoef[2] * s2v +
                   scoef[3] * s3v + scoef[4] * s4v;
        sw_[n] = dlane * t5;
        cbv = t5;
        #pragma unroll
        for (int off = 32; off; off >>= 1) cbv += __shfl_down(cbv, off, 64);
        // a[m] = sum_n w[n]*adj_l[n][m] partials — wave h covers n in [16h,16h+16)
        float pa = 0.f;
        #pragma unroll
        for (int i = 0; i < 16; ++i) {
            const int nn2 = h * 16 + i;
            const float al = (nn2 == n) ? 1.f
                           : (float)((sadjb[nn2][n >> 2] >> ((n & 3) * 8)) & 255u);
            pa += sw_[nn2] * al;    // sw_ written by this same wave
        }
        u.s.A[h][n] = pa;           // A free since B4
    }
    __syncthreads();   // B6

    // ---- S7: wave0 final: out = sum_m d[m]*a[m]*q[m] + cb*b1z + 5*b2wl + bl ----
    if (wv == 0) {
        const float a = u.s.A[0][n] + u.s.A[1][n] + u.s.A[2][n] + u.s.A[3][n];
        float v = dlane * a * sq[n];
        #pragma unroll
        for (int off = 32; off; off >>= 1) v += __shfl_down(v, off, 64);
        if (lane == 0)
            out[g] = v + cbv * c_b1z + 5.f * c_b2w + c_bl;
    }
}

extern "C" void kernel_launch(void* const* d_in, const int* in_sizes, int n_in,
                              void* d_out, int out_size, void* d_ws, size_t ws_size,
                              hipStream_t stream) {
    const float* x  = (const float*)d_in[0];
    const int*   ei = (const int*)d_in[1];
    // d_in[2] = batch (layout implied; unused)
    const float* Wp = (const float*)d_in[3];
    const float* bp = (const float*)d_in[4];
    const float* W1 = (const float*)d_in[5];
    const float* b1 = (const float*)d_in[6];
    const float* W2 = (const float*)d_in[7];
    const float* b2 = (const float*)d_in[8];
    const float* Wl = (const float*)d_in[9];
    const float* bl = (const float*)d_in[10];
    float* out = (float*)d_out;
    float* ws  = (float*)d_ws;

    const int B = out_size;            // 8192 graphs
    const int E = in_sizes[1] / 2;     // edge_index is [2, E]
    const int epg = E / B;             // 512 edges per graph

    zprep<<<5, 64, 0, stream>>>(W1, Wp, W2, Wl, b1, b2, ws);
    diffpool_main<<<B, 256, 0, stream>>>(x, ei, bp, bl, ws, out, E, epg);
}